// Round 6
// baseline (559.228 us; speedup 1.0000x reference)
//
#include <hip/hip_runtime.h>
#include <hip/hip_bf16.h>
#include <math.h>

#define N_NODES 5000
#define N_ELEMS 10
#define C_DIM   128
#define N_EDGE  100000
#define N_BES   8
#define RAD_H   64
#define NL      4
#define SH_DIM  16
#define ONODES  8

// scales
#define SC_SCALE 0.02795084971874737f    // 1/sqrt(128*10)
#define X_SCALE  0.08838834764831845f    // 1/sqrt(128)
#define R1_SCALE 0.3535533905932738f     // 1/sqrt(8)
#define R_SCALE  0.125f                  // 1/sqrt(64)
#define OUT_SCALE 0.004419417382415922f  // (1/sqrt(128))/20

__device__ __forceinline__ float silu(float v) { return v / (1.f + __expf(-v)); }

// ---------------- node kernel: sc + x ----------------
__global__ __launch_bounds__(128) void node_kernel(
    const float* __restrict__ node_attrs, const float* __restrict__ node_feats,
    const float* __restrict__ w_skip, const float* __restrict__ w_up,
    float* __restrict__ x, float* __restrict__ sc_out)
{
    int n = blockIdx.x, t = threadIdx.x;
    __shared__ float f[C_DIM];
    __shared__ float at[N_ELEMS];
    f[t] = node_feats[(size_t)n * C_DIM + t];
    if (t < N_ELEMS) at[t] = node_attrs[(size_t)n * N_ELEMS + t];
    __syncthreads();

    float acc = 0.f;
    for (int a = 0; a < N_ELEMS; ++a) {
        float av = at[a];
        if (av != 0.f) {
            const float* wp = w_skip + a * C_DIM + t;
            float s2 = 0.f;
            #pragma unroll 8
            for (int c = 0; c < C_DIM; ++c) s2 += f[c] * wp[(size_t)c * (N_ELEMS * C_DIM)];
            acc += av * s2;
        }
    }
    sc_out[(size_t)n * C_DIM + t] = acc * SC_SCALE;

    float xa = 0.f;
    #pragma unroll 8
    for (int k = 0; k < C_DIM; ++k) xa += f[k] * w_up[k * C_DIM + t];
    x[(size_t)n * C_DIM + t] = xa * X_SCALE;
}

// ---------------- radial MLP layers 1-3 -> h3 ----------------
__global__ __launch_bounds__(256) void radial_kernel(
    const float* __restrict__ edge_feats,
    const float* __restrict__ w1, const float* __restrict__ w2, const float* __restrict__ w3,
    float* __restrict__ h3out)
{
    __shared__ float w1s[N_BES * RAD_H];
    __shared__ float w2s[RAD_H * RAD_H];
    __shared__ float w3s[RAD_H * RAD_H];
    __shared__ float h1s[4][RAD_H];
    __shared__ float h2s[4][RAD_H];
    int t = threadIdx.x;
    for (int i = t; i < N_BES * RAD_H; i += 256) w1s[i] = w1[i];
    for (int i = t; i < RAD_H * RAD_H; i += 256) { w2s[i] = w2[i]; w3s[i] = w3[i]; }
    __syncthreads();
    int sub = t >> 6, j = t & 63;
    for (int e0 = blockIdx.x * 4; e0 < N_EDGE; e0 += gridDim.x * 4) {
        int e = e0 + sub;
        if (e < N_EDGE) {
            const float4* ef = (const float4*)(edge_feats + (size_t)e * N_BES);
            float4 f0 = ef[0], f1 = ef[1];
            float a = f0.x * w1s[0 * RAD_H + j] + f0.y * w1s[1 * RAD_H + j]
                    + f0.z * w1s[2 * RAD_H + j] + f0.w * w1s[3 * RAD_H + j]
                    + f1.x * w1s[4 * RAD_H + j] + f1.y * w1s[5 * RAD_H + j]
                    + f1.z * w1s[6 * RAD_H + j] + f1.w * w1s[7 * RAD_H + j];
            h1s[sub][j] = silu(a * R1_SCALE);
        }
        __syncthreads();
        if (e < N_EDGE) {
            const float4* h4 = (const float4*)h1s[sub];
            float a = 0.f;
            #pragma unroll
            for (int kk = 0; kk < RAD_H / 4; ++kk) {
                float4 h = h4[kk];
                int k = kk * 4;
                a += h.x * w2s[(k + 0) * RAD_H + j] + h.y * w2s[(k + 1) * RAD_H + j]
                   + h.z * w2s[(k + 2) * RAD_H + j] + h.w * w2s[(k + 3) * RAD_H + j];
            }
            h2s[sub][j] = silu(a * R_SCALE);
        }
        __syncthreads();
        if (e < N_EDGE) {
            const float4* h4 = (const float4*)h2s[sub];
            float a = 0.f;
            #pragma unroll
            for (int kk = 0; kk < RAD_H / 4; ++kk) {
                float4 h = h4[kk];
                int k = kk * 4;
                a += h.x * w3s[(k + 0) * RAD_H + j] + h.y * w3s[(k + 1) * RAD_H + j]
                   + h.z * w3s[(k + 2) * RAD_H + j] + h.w * w3s[(k + 3) * RAD_H + j];
            }
            h3out[(size_t)e * RAD_H + j] = silu(a * R_SCALE);
        }
        __syncthreads();
    }
}

// ---------------- CSR build ----------------
__global__ void hist_kernel(const int* __restrict__ recv, int* __restrict__ deg)
{
    int e = blockIdx.x * 256 + threadIdx.x;
    if (e < N_EDGE) atomicAdd(&deg[recv[e]], 1);
}

__global__ __launch_bounds__(256) void scan_kernel(const int* __restrict__ deg, int* __restrict__ offs)
{
    __shared__ int sums[256];
    int t = threadIdx.x;
    int base = t * 20;
    int loc[20]; int s = 0;
    #pragma unroll
    for (int i = 0; i < 20; ++i) { int idx = base + i; int v = (idx < N_NODES) ? deg[idx] : 0; loc[i] = s; s += v; }
    sums[t] = s; __syncthreads();
    for (int off = 1; off < 256; off <<= 1) {
        int v = (t >= off) ? sums[t - off] : 0;
        __syncthreads();
        sums[t] += v;
        __syncthreads();
    }
    int ex = (t == 0) ? 0 : sums[t - 1];
    #pragma unroll
    for (int i = 0; i < 20; ++i) { int idx = base + i; if (idx < N_NODES) offs[idx] = ex + loc[i]; }
    if (t == 255) offs[N_NODES] = sums[255];
}

__global__ void scatter_kernel(const int* __restrict__ recv, const int* __restrict__ offs,
                               int* __restrict__ cursor, int* __restrict__ perm)
{
    int e = blockIdx.x * 256 + threadIdx.x;
    if (e < N_EDGE) {
        int r = recv[e];
        int pos = atomicAdd(&cursor[r], 1);
        perm[offs[r] + pos] = e;
    }
}

// ---------------- fused gather: tp_w recompute + message accumulate ----------------
// One block per node, 512 threads: (l = t>>7, c = t&127).
// w_rad4 column pinned in VGPRs via keep-alive asm; h3 row via scalar loads.
__global__ __launch_bounds__(512, 4) void fused_gather_kernel(
    const int* __restrict__ perm, const int* __restrict__ offs,
    const int* __restrict__ sender, const float* __restrict__ x,
    const float* __restrict__ edge_attrs, const float* __restrict__ h3,
    const float* __restrict__ w4, float* __restrict__ msg)
{
    int n = blockIdx.x, t = threadIdx.x;
    int c = t & 127, l = t >> 7;
    float wc[RAD_H];
    #pragma unroll
    for (int k = 0; k < RAD_H; ++k)
        wc[k] = w4[k * (NL * C_DIM) + l * C_DIM + c];
    // pin into VGPRs: prevent rematerialization/reload inside the edge loop
    #pragma unroll
    for (int k = 0; k < RAD_H; ++k) asm volatile("" : "+v"(wc[k]));

    float acc[7] = {0.f, 0.f, 0.f, 0.f, 0.f, 0.f, 0.f};
    int nm = 2 * l + 1;
    int start = offs[n], end = offs[n + 1];
    for (int idx = start; idx < end; ++idx) {
        int e = __builtin_amdgcn_readfirstlane(perm[idx]);
        int s = __builtin_amdgcn_readfirstlane(sender[e]);
        float xv = x[(size_t)s * C_DIM + c];
        const float* h3r = h3 + (size_t)e * RAD_H;     // uniform -> scalar loads
        float tp = 0.f;
        #pragma unroll
        for (int k = 0; k < RAD_H; ++k) tp += h3r[k] * wc[k];
        float xt = xv * (tp * R_SCALE);
        const float* ear = edge_attrs + (size_t)e * SH_DIM + l * l;
        #pragma unroll
        for (int j = 0; j < 7; ++j)
            if (j < nm) acc[j] += ear[j] * xt;
    }
    float* mout = msg + (size_t)n * (SH_DIM * C_DIM) + (size_t)(l * l) * C_DIM + c;
    #pragma unroll
    for (int j = 0; j < 7; ++j)
        if (j < nm) mout[(size_t)j * C_DIM] = acc[j];
}

// ---------------- out[n,m,d] = sum_c msg[n,m,c]*w_out[l(m),c,d]  (in place on d_out) ----------------
// 8 nodes/block; msgs (64 KB) + w_out panel (64 KB) in LDS; 4x4 register tile/thread.
__global__ __launch_bounds__(256) void out_kernel(
    float* __restrict__ out, const float* __restrict__ w_out)
{
    __shared__ float msgs[ONODES * SH_DIM * C_DIM];   // 64 KB
    __shared__ float wlds[C_DIM * C_DIM];             // 64 KB
    int nb = blockIdx.x * ONODES, t = threadIdx.x;
    {
        const float4* src = (const float4*)(out + (size_t)nb * SH_DIM * C_DIM);
        float4* dst = (float4*)msgs;
        for (int i = t; i < ONODES * SH_DIM * C_DIM / 4; i += 256) dst[i] = src[i];
    }
    int dq = t & 31, rg = t >> 5;
    int d0 = dq * 4;
    #pragma unroll
    for (int l = 0; l < 4; ++l) {
        __syncthreads();   // protect wlds from previous readers (and msgs staging on l=0)
        {
            const float4* src = (const float4*)(w_out + (size_t)l * C_DIM * C_DIM);
            float4* dst = (float4*)wlds;
            for (int i = t; i < C_DIM * C_DIM / 4; i += 256) dst[i] = src[i];
        }
        __syncthreads();
        const int ms = l * l, cnt = 2 * l + 1;
        const int ntiles = ONODES * cnt / 4;          // 2,6,10,14
        for (int ti = rg; ti < ntiles; ti += 8) {
            int r0 = ti * 4;
            int rbase[4]; size_t obase[4];
            #pragma unroll
            for (int i = 0; i < 4; ++i) {
                int r = r0 + i;
                int node = r / cnt, mm = ms + r % cnt;   // cnt compile-time (l unrolled)
                rbase[i] = (node * SH_DIM + mm) * C_DIM;
                obase[i] = ((size_t)(nb + node) * SH_DIM + mm) * C_DIM + d0;
            }
            float acc[4][4] = {};
            for (int k = 0; k < C_DIM; k += 4) {
                float4 b0 = *(const float4*)&wlds[(k + 0) * C_DIM + d0];
                float4 b1 = *(const float4*)&wlds[(k + 1) * C_DIM + d0];
                float4 b2 = *(const float4*)&wlds[(k + 2) * C_DIM + d0];
                float4 b3 = *(const float4*)&wlds[(k + 3) * C_DIM + d0];
                #pragma unroll
                for (int i = 0; i < 4; ++i) {
                    float4 a = *(const float4*)&msgs[rbase[i] + k];
                    acc[i][0] += a.x * b0.x + a.y * b1.x + a.z * b2.x + a.w * b3.x;
                    acc[i][1] += a.x * b0.y + a.y * b1.y + a.z * b2.y + a.w * b3.y;
                    acc[i][2] += a.x * b0.z + a.y * b1.z + a.z * b2.z + a.w * b3.z;
                    acc[i][3] += a.x * b0.w + a.y * b1.w + a.z * b2.w + a.w * b3.w;
                }
            }
            #pragma unroll
            for (int i = 0; i < 4; ++i) {
                float4 r4 = make_float4(acc[i][0] * OUT_SCALE, acc[i][1] * OUT_SCALE,
                                        acc[i][2] * OUT_SCALE, acc[i][3] * OUT_SCALE);
                *(float4*)(out + obase[i]) = r4;
            }
        }
    }
}

extern "C" void kernel_launch(void* const* d_in, const int* in_sizes, int n_in,
                              void* d_out, int out_size, void* d_ws, size_t ws_size,
                              hipStream_t stream)
{
    const float* node_attrs = (const float*)d_in[0];
    const float* node_feats = (const float*)d_in[1];
    const float* edge_attrs = (const float*)d_in[2];
    const float* edge_feats = (const float*)d_in[3];
    const int*   edge_index = (const int*)d_in[4];
    const float* w_up   = (const float*)d_in[5];
    const float* w_rad1 = (const float*)d_in[6];
    const float* w_rad2 = (const float*)d_in[7];
    const float* w_rad3 = (const float*)d_in[8];
    const float* w_rad4 = (const float*)d_in[9];
    const float* w_skip = (const float*)d_in[10];
    const float* w_out  = (const float*)d_in[11];
    const int* sender = edge_index;
    const int* recv   = edge_index + N_EDGE;

    float* out = (float*)d_out;                                 // msg staged here, then in-place
    float* sc  = out + (size_t)N_NODES * SH_DIM * C_DIM;

    // workspace (28.6 MB; ws_size >= 69 MB known from round-4 evidence)
    float* x   = (float*)d_ws;
    float* h3  = x + (size_t)N_NODES * C_DIM;
    int* deg    = (int*)(h3 + (size_t)N_EDGE * RAD_H);
    int* cursor = deg + 5120;
    int* offs   = cursor + 5120;
    int* perm   = offs + 5124;

    hipMemsetAsync(deg, 0, 2 * 5120 * sizeof(int), stream);

    node_kernel<<<N_NODES, 128, 0, stream>>>(node_attrs, node_feats, w_skip, w_up, x, sc);
    radial_kernel<<<1024, 256, 0, stream>>>(edge_feats, w_rad1, w_rad2, w_rad3, h3);

    hist_kernel<<<(N_EDGE + 255) / 256, 256, 0, stream>>>(recv, deg);
    scan_kernel<<<1, 256, 0, stream>>>(deg, offs);
    scatter_kernel<<<(N_EDGE + 255) / 256, 256, 0, stream>>>(recv, offs, cursor, perm);

    fused_gather_kernel<<<N_NODES, 512, 0, stream>>>(perm, offs, sender, x, edge_attrs, h3, w_rad4, out);
    out_kernel<<<N_NODES / ONODES, 256, 0, stream>>>(out, w_out);
}

// Round 7
// 481.386 us; speedup vs baseline: 1.1617x; 1.1617x over previous
//
#include <hip/hip_runtime.h>
#include <hip/hip_bf16.h>
#include <math.h>

#define N_NODES 5000
#define N_ELEMS 10
#define C_DIM   128
#define N_EDGE  100000
#define N_BES   8
#define RAD_H   64
#define NL      4
#define SH_DIM  16
#define ONODES  8

// scales
#define SC_SCALE 0.02795084971874737f    // 1/sqrt(128*10)
#define X_SCALE  0.08838834764831845f    // 1/sqrt(128)
#define R1_SCALE 0.3535533905932738f     // 1/sqrt(8)
#define R_SCALE  0.125f                  // 1/sqrt(64)
#define OUT_SCALE 0.004419417382415922f  // (1/sqrt(128))/20

__device__ __forceinline__ float silu(float v) { return v / (1.f + __expf(-v)); }

// ---------------- node kernel: sc + x ----------------
__global__ __launch_bounds__(128) void node_kernel(
    const float* __restrict__ node_attrs, const float* __restrict__ node_feats,
    const float* __restrict__ w_skip, const float* __restrict__ w_up,
    float* __restrict__ x, float* __restrict__ sc_out)
{
    int n = blockIdx.x, t = threadIdx.x;
    __shared__ float f[C_DIM];
    __shared__ float at[N_ELEMS];
    f[t] = node_feats[(size_t)n * C_DIM + t];
    if (t < N_ELEMS) at[t] = node_attrs[(size_t)n * N_ELEMS + t];
    __syncthreads();

    float acc = 0.f;
    for (int a = 0; a < N_ELEMS; ++a) {
        float av = at[a];
        if (av != 0.f) {
            const float* wp = w_skip + a * C_DIM + t;
            float s2 = 0.f;
            #pragma unroll 8
            for (int c = 0; c < C_DIM; ++c) s2 += f[c] * wp[(size_t)c * (N_ELEMS * C_DIM)];
            acc += av * s2;
        }
    }
    sc_out[(size_t)n * C_DIM + t] = acc * SC_SCALE;

    float xa = 0.f;
    #pragma unroll 8
    for (int k = 0; k < C_DIM; ++k) xa += f[k] * w_up[k * C_DIM + t];
    x[(size_t)n * C_DIM + t] = xa * X_SCALE;
}

// ---------------- radial MLP layers 1-3 -> h3 ----------------
__global__ __launch_bounds__(256) void radial_kernel(
    const float* __restrict__ edge_feats,
    const float* __restrict__ w1, const float* __restrict__ w2, const float* __restrict__ w3,
    float* __restrict__ h3out)
{
    __shared__ float w1s[N_BES * RAD_H];
    __shared__ float w2s[RAD_H * RAD_H];
    __shared__ float w3s[RAD_H * RAD_H];
    __shared__ float h1s[4][RAD_H];
    __shared__ float h2s[4][RAD_H];
    int t = threadIdx.x;
    for (int i = t; i < N_BES * RAD_H; i += 256) w1s[i] = w1[i];
    for (int i = t; i < RAD_H * RAD_H; i += 256) { w2s[i] = w2[i]; w3s[i] = w3[i]; }
    __syncthreads();
    int sub = t >> 6, j = t & 63;
    for (int e0 = blockIdx.x * 4; e0 < N_EDGE; e0 += gridDim.x * 4) {
        int e = e0 + sub;
        if (e < N_EDGE) {
            const float4* ef = (const float4*)(edge_feats + (size_t)e * N_BES);
            float4 f0 = ef[0], f1 = ef[1];
            float a = f0.x * w1s[0 * RAD_H + j] + f0.y * w1s[1 * RAD_H + j]
                    + f0.z * w1s[2 * RAD_H + j] + f0.w * w1s[3 * RAD_H + j]
                    + f1.x * w1s[4 * RAD_H + j] + f1.y * w1s[5 * RAD_H + j]
                    + f1.z * w1s[6 * RAD_H + j] + f1.w * w1s[7 * RAD_H + j];
            h1s[sub][j] = silu(a * R1_SCALE);
        }
        __syncthreads();
        if (e < N_EDGE) {
            const float4* h4 = (const float4*)h1s[sub];
            float a = 0.f;
            #pragma unroll
            for (int kk = 0; kk < RAD_H / 4; ++kk) {
                float4 h = h4[kk];
                int k = kk * 4;
                a += h.x * w2s[(k + 0) * RAD_H + j] + h.y * w2s[(k + 1) * RAD_H + j]
                   + h.z * w2s[(k + 2) * RAD_H + j] + h.w * w2s[(k + 3) * RAD_H + j];
            }
            h2s[sub][j] = silu(a * R_SCALE);
        }
        __syncthreads();
        if (e < N_EDGE) {
            const float4* h4 = (const float4*)h2s[sub];
            float a = 0.f;
            #pragma unroll
            for (int kk = 0; kk < RAD_H / 4; ++kk) {
                float4 h = h4[kk];
                int k = kk * 4;
                a += h.x * w3s[(k + 0) * RAD_H + j] + h.y * w3s[(k + 1) * RAD_H + j]
                   + h.z * w3s[(k + 2) * RAD_H + j] + h.w * w3s[(k + 3) * RAD_H + j];
            }
            h3out[(size_t)e * RAD_H + j] = silu(a * R_SCALE);
        }
        __syncthreads();
    }
}

// ---------------- CSR build ----------------
__global__ void hist_kernel(const int* __restrict__ recv, int* __restrict__ deg)
{
    int e = blockIdx.x * 256 + threadIdx.x;
    if (e < N_EDGE) atomicAdd(&deg[recv[e]], 1);
}

__global__ __launch_bounds__(256) void scan_kernel(const int* __restrict__ deg, int* __restrict__ offs)
{
    __shared__ int sums[256];
    int t = threadIdx.x;
    int base = t * 20;
    int loc[20]; int s = 0;
    #pragma unroll
    for (int i = 0; i < 20; ++i) { int idx = base + i; int v = (idx < N_NODES) ? deg[idx] : 0; loc[i] = s; s += v; }
    sums[t] = s; __syncthreads();
    for (int off = 1; off < 256; off <<= 1) {
        int v = (t >= off) ? sums[t - off] : 0;
        __syncthreads();
        sums[t] += v;
        __syncthreads();
    }
    int ex = (t == 0) ? 0 : sums[t - 1];
    #pragma unroll
    for (int i = 0; i < 20; ++i) { int idx = base + i; if (idx < N_NODES) offs[idx] = ex + loc[i]; }
    if (t == 255) offs[N_NODES] = sums[255];
}

__global__ void scatter_kernel(const int* __restrict__ recv, const int* __restrict__ offs,
                               int* __restrict__ cursor, int* __restrict__ perm)
{
    int e = blockIdx.x * 256 + threadIdx.x;
    if (e < N_EDGE) {
        int r = recv[e];
        int pos = atomicAdd(&cursor[r], 1);
        perm[offs[r] + pos] = e;
    }
}

// ---------------- fused gather: tp_w recompute + message accumulate ----------------
// One block per node, 512 threads: (l = t>>7, c = t&127).
// wc[64] pinned in VGPRs: opaque "+v" asm INSIDE the edge loop forbids
// rematerialization of the w4 loads (round-6 failure mode: VGPR=44, wc
// reloaded from L1/L2 per edge -> 12.8 TB cache traffic).
__global__ __launch_bounds__(512, 4) void fused_gather_kernel(
    const int* __restrict__ perm, const int* __restrict__ offs,
    const int* __restrict__ sender, const float* __restrict__ x,
    const float* __restrict__ edge_attrs, const float* __restrict__ h3,
    const float* __restrict__ w4, float* __restrict__ msg)
{
    int n = blockIdx.x, t = threadIdx.x;
    int c = t & 127, l = t >> 7;
    float wc[RAD_H];
    #pragma unroll
    for (int k = 0; k < RAD_H; ++k)
        wc[k] = w4[k * (NL * C_DIM) + l * C_DIM + c];

    float acc[7] = {0.f, 0.f, 0.f, 0.f, 0.f, 0.f, 0.f};
    int nm = 2 * l + 1;
    int start = offs[n], end = offs[n + 1];
    if (start < end) {
        int e = __builtin_amdgcn_readfirstlane(perm[start]);
        int s = __builtin_amdgcn_readfirstlane(sender[e]);
        for (int idx = start; idx < end; ++idx) {
            // pin wc in VGPRs: values "may be modified" -> no remat from w4
            #pragma unroll
            for (int k = 0; k < RAD_H; k += 8)
                asm volatile("" : "+v"(wc[k]), "+v"(wc[k+1]), "+v"(wc[k+2]), "+v"(wc[k+3]),
                                  "+v"(wc[k+4]), "+v"(wc[k+5]), "+v"(wc[k+6]), "+v"(wc[k+7]));
            int e_cur = e, s_cur = s;
            if (idx + 1 < end) {                      // prefetch next indices
                e = __builtin_amdgcn_readfirstlane(perm[idx + 1]);
                s = __builtin_amdgcn_readfirstlane(sender[e]);
            }
            const float* h3r = h3 + (size_t)e_cur * RAD_H;   // uniform -> scalar loads
            float xv = x[(size_t)s_cur * C_DIM + c];
            float tp0 = 0.f, tp1 = 0.f, tp2 = 0.f, tp3 = 0.f;  // 4 chains: ILP
            #pragma unroll
            for (int q = 0; q < RAD_H / 4; ++q) {
                tp0 += h3r[4 * q + 0] * wc[4 * q + 0];
                tp1 += h3r[4 * q + 1] * wc[4 * q + 1];
                tp2 += h3r[4 * q + 2] * wc[4 * q + 2];
                tp3 += h3r[4 * q + 3] * wc[4 * q + 3];
            }
            float tp = (tp0 + tp1) + (tp2 + tp3);
            float xt = xv * (tp * R_SCALE);
            const float* ear = edge_attrs + (size_t)e_cur * SH_DIM + l * l;
            #pragma unroll
            for (int j = 0; j < 7; ++j)
                if (j < nm) acc[j] += ear[j] * xt;
        }
    }
    float* mout = msg + (size_t)n * (SH_DIM * C_DIM) + (size_t)(l * l) * C_DIM + c;
    #pragma unroll
    for (int j = 0; j < 7; ++j)
        if (j < nm) mout[(size_t)j * C_DIM] = acc[j];
}

// ---------------- out[n,m,d] = sum_c msg[n,m,c]*w_out[l(m),c,d]  (in place on d_out) ----------------
__global__ __launch_bounds__(256) void out_kernel(
    float* __restrict__ out, const float* __restrict__ w_out)
{
    __shared__ float msgs[ONODES * SH_DIM * C_DIM];   // 64 KB
    __shared__ float wlds[C_DIM * C_DIM];             // 64 KB
    int nb = blockIdx.x * ONODES, t = threadIdx.x;
    {
        const float4* src = (const float4*)(out + (size_t)nb * SH_DIM * C_DIM);
        float4* dst = (float4*)msgs;
        for (int i = t; i < ONODES * SH_DIM * C_DIM / 4; i += 256) dst[i] = src[i];
    }
    int dq = t & 31, rg = t >> 5;
    int d0 = dq * 4;
    #pragma unroll
    for (int l = 0; l < 4; ++l) {
        __syncthreads();
        {
            const float4* src = (const float4*)(w_out + (size_t)l * C_DIM * C_DIM);
            float4* dst = (float4*)wlds;
            for (int i = t; i < C_DIM * C_DIM / 4; i += 256) dst[i] = src[i];
        }
        __syncthreads();
        const int ms = l * l, cnt = 2 * l + 1;
        const int ntiles = ONODES * cnt / 4;
        for (int ti = rg; ti < ntiles; ti += 8) {
            int r0 = ti * 4;
            int rbase[4]; size_t obase[4];
            #pragma unroll
            for (int i = 0; i < 4; ++i) {
                int r = r0 + i;
                int node = r / cnt, mm = ms + r % cnt;
                rbase[i] = (node * SH_DIM + mm) * C_DIM;
                obase[i] = ((size_t)(nb + node) * SH_DIM + mm) * C_DIM + d0;
            }
            float acc[4][4] = {};
            for (int k = 0; k < C_DIM; k += 4) {
                float4 b0 = *(const float4*)&wlds[(k + 0) * C_DIM + d0];
                float4 b1 = *(const float4*)&wlds[(k + 1) * C_DIM + d0];
                float4 b2 = *(const float4*)&wlds[(k + 2) * C_DIM + d0];
                float4 b3 = *(const float4*)&wlds[(k + 3) * C_DIM + d0];
                #pragma unroll
                for (int i = 0; i < 4; ++i) {
                    float4 a = *(const float4*)&msgs[rbase[i] + k];
                    acc[i][0] += a.x * b0.x + a.y * b1.x + a.z * b2.x + a.w * b3.x;
                    acc[i][1] += a.x * b0.y + a.y * b1.y + a.z * b2.y + a.w * b3.y;
                    acc[i][2] += a.x * b0.z + a.y * b1.z + a.z * b2.z + a.w * b3.z;
                    acc[i][3] += a.x * b0.w + a.y * b1.w + a.z * b2.w + a.w * b3.w;
                }
            }
            #pragma unroll
            for (int i = 0; i < 4; ++i) {
                float4 r4 = make_float4(acc[i][0] * OUT_SCALE, acc[i][1] * OUT_SCALE,
                                        acc[i][2] * OUT_SCALE, acc[i][3] * OUT_SCALE);
                *(float4*)(out + obase[i]) = r4;
            }
        }
    }
}

extern "C" void kernel_launch(void* const* d_in, const int* in_sizes, int n_in,
                              void* d_out, int out_size, void* d_ws, size_t ws_size,
                              hipStream_t stream)
{
    const float* node_attrs = (const float*)d_in[0];
    const float* node_feats = (const float*)d_in[1];
    const float* edge_attrs = (const float*)d_in[2];
    const float* edge_feats = (const float*)d_in[3];
    const int*   edge_index = (const int*)d_in[4];
    const float* w_up   = (const float*)d_in[5];
    const float* w_rad1 = (const float*)d_in[6];
    const float* w_rad2 = (const float*)d_in[7];
    const float* w_rad3 = (const float*)d_in[8];
    const float* w_rad4 = (const float*)d_in[9];
    const float* w_skip = (const float*)d_in[10];
    const float* w_out  = (const float*)d_in[11];
    const int* sender = edge_index;
    const int* recv   = edge_index + N_EDGE;

    float* out = (float*)d_out;                                 // msg staged here, then in-place
    float* sc  = out + (size_t)N_NODES * SH_DIM * C_DIM;

    // workspace (28.6 MB; ws_size >= 69 MB known from round-4 evidence)
    float* x   = (float*)d_ws;
    float* h3  = x + (size_t)N_NODES * C_DIM;
    int* deg    = (int*)(h3 + (size_t)N_EDGE * RAD_H);
    int* cursor = deg + 5120;
    int* offs   = cursor + 5120;
    int* perm   = offs + 5124;

    hipMemsetAsync(deg, 0, 2 * 5120 * sizeof(int), stream);

    node_kernel<<<N_NODES, 128, 0, stream>>>(node_attrs, node_feats, w_skip, w_up, x, sc);
    radial_kernel<<<1024, 256, 0, stream>>>(edge_feats, w_rad1, w_rad2, w_rad3, h3);

    hist_kernel<<<(N_EDGE + 255) / 256, 256, 0, stream>>>(recv, deg);
    scan_kernel<<<1, 256, 0, stream>>>(deg, offs);
    scatter_kernel<<<(N_EDGE + 255) / 256, 256, 0, stream>>>(recv, offs, cursor, perm);

    fused_gather_kernel<<<N_NODES, 512, 0, stream>>>(perm, offs, sender, x, edge_attrs, h3, w_rad4, out);
    out_kernel<<<N_NODES / ONODES, 256, 0, stream>>>(out, w_out);
}